// Round 8
// baseline (93.124 us; speedup 1.0000x reference)
//
#include <hip/hip_runtime.h>
#include <cstdint>

#define NCELLS (48*48*48)   // 110592
#define NT 48
#define CB 64               // cells per tile
#define TILES 4             // tiles per block (256 cells/block)
#define NBLK (NCELLS / (CB * TILES))   // 432
#define NW 8                // waves per block; each wave does 6 tris
#define PITCH 97            // topo LDS row pitch (97 % 32 == 1 -> 2 lanes/bank = free)
#define OFFE (3*2*7*49)     // staged off region: 3a * 2dx * 7ly * 49z = 2058 floats

// ---------------- compile-time exact numpy RNG reproduction ----------------
namespace nprng {
typedef unsigned __int128 u128;
struct PCG { u128 state; u128 inc; int has32; uint32_t cached; };

constexpr u128 mult128() {
  return (((u128)2549297995355413924ULL) << 64) | (u128)4865540595714422341ULL;
}
constexpr void step(PCG& g) { g.state = g.state * mult128() + g.inc; }
constexpr uint64_t out64(const PCG& g) {
  uint64_t x = (uint64_t)(g.state >> 64) ^ (uint64_t)g.state;
  unsigned rot = (unsigned)(g.state >> 122);
  return (x >> rot) | (x << ((64u - rot) & 63u));
}
constexpr uint64_t next64(PCG& g) { step(g); return out64(g); }
constexpr uint32_t next32(PCG& g) {
  if (g.has32) { g.has32 = 0; return g.cached; }
  uint64_t v = next64(g);
  g.has32 = 1; g.cached = (uint32_t)(v >> 32);
  return (uint32_t)v;
}
constexpr uint32_t lemire32(PCG& g, uint32_t rngmax) {
  const uint32_t rng_excl = rngmax + 1u;
  uint64_t m = (uint64_t)next32(g) * (uint64_t)rng_excl;
  uint32_t leftover = (uint32_t)m;
  if (leftover < rng_excl) {
    const uint32_t threshold = (uint32_t)((0xFFFFFFFFu - rngmax) % rng_excl);
    while (leftover < threshold) {
      m = (uint64_t)next32(g) * (uint64_t)rng_excl;
      leftover = (uint32_t)m;
    }
  }
  return (uint32_t)(m >> 32);
}
constexpr uint64_t rbu(PCG& g, uint64_t rngmax) {
  if (rngmax == 0) return 0;
  return (uint64_t)lemire32(g, (uint32_t)rngmax);
}
constexpr uint32_t hashmix(uint32_t v, uint32_t& hc) {
  v ^= hc; hc *= 0x931e8875u; v *= hc; v ^= v >> 16; return v;
}
constexpr uint32_t mix2(uint32_t x, uint32_t y) {
  uint32_t r = 0xca01f9ddu * x - 0x4973f715u * y; r ^= r >> 16; return r;
}
constexpr PCG seed_pcg0() {
  PCG g{0, 0, 0, 0};
  uint32_t pool[4] = {};
  uint32_t hc = 0x43b0d7e5u;
  for (int i = 0; i < 4; i++) pool[i] = hashmix(0u, hc);
  for (int s = 0; s < 4; s++)
    for (int d = 0; d < 4; d++)
      if (s != d) pool[d] = mix2(pool[d], hashmix(pool[s], hc));
  uint32_t st[8] = {};
  uint32_t hb = 0x8b51f9ddu;
  for (int i = 0; i < 8; i++) {
    uint32_t v = pool[i & 3];
    v ^= hb; hb *= 0x58f38dedu; v *= hb; v ^= v >> 16;
    st[i] = v;
  }
  uint64_t w[4] = {};
  for (int i = 0; i < 4; i++) w[i] = (uint64_t)st[2 * i] | ((uint64_t)st[2 * i + 1] << 32);
  u128 initstate = (((u128)w[0]) << 64) | (u128)w[1];
  u128 initseq   = (((u128)w[2]) << 64) | (u128)w[3];
  g.state = 0; g.inc = (initseq << 1) | (u128)1;
  step(g); g.state += initstate; step(g);
  g.has32 = 0; g.cached = 0;
  return g;
}
constexpr void choice_nr(PCG& g, int pop, int n, int* outv, bool shuf) {
  uint64_t hs[64] = {};
  uint64_t set_size = (uint64_t)(1.2 * (double)n);
  uint64_t mask = set_size;
  mask |= mask >> 1; mask |= mask >> 2; mask |= mask >> 4;
  mask |= mask >> 8; mask |= mask >> 16; mask |= mask >> 32;
  for (int i = 0; i < 64; i++) hs[i] = ~0ULL;
  for (int j = pop - n; j < pop; j++) {
    uint64_t val = rbu(g, (uint64_t)j);
    uint64_t loc = val & mask;
    while (hs[loc] != ~0ULL && hs[loc] != val) loc = (loc + 1) & mask;
    if (hs[loc] == ~0ULL) { hs[loc] = val; outv[j - (pop - n)] = (int)val; }
    else {
      loc = (uint64_t)j & mask;
      while (hs[loc] != ~0ULL) loc = (loc + 1) & mask;
      hs[loc] = (uint64_t)j;
      outv[j - (pop - n)] = j;
    }
  }
  if (shuf) {
    for (int i = n - 1; i >= 1; i--) {
      uint64_t j = rbu(g, (uint64_t)i);
      int t = outv[i]; outv[i] = outv[(int)j]; outv[(int)j] = t;
    }
  }
}
} // namespace nprng

struct TriTab3 {
  float ub[NT][3];
  float wb[NT][3];
  int   a0[NT], a1[NT], a2[NT];
  int   lofc[NT][3];   // LDS off index const: ((a*2+cx)*7+cy)*49 + cz
  int   tto[NT];
};

constexpr TriTab3 make_tab() {
  TriTab3 T{};
  nprng::PCG g = nprng::seed_pcg0();
  int tri[NT][3] = {};
  for (int t = 0; t < NT; t++) nprng::choice_nr(g, 12, 3, tri[t], true);
  int tt[NT] = {};
  nprng::choice_nr(g, 96, NT, tt, true);
  for (int i = 1; i < NT; i++) {
    int v = tt[i], j = i - 1;
    while (j >= 0 && tt[j] > v) { tt[j + 1] = tt[j]; j--; }
    tt[j + 1] = v;
  }
  constexpr int EC[12][3] = {{0,0,0},{0,1,0},{0,0,1},{0,1,1},
                             {0,0,0},{1,0,0},{0,0,1},{1,0,1},
                             {0,0,0},{1,0,0},{0,1,0},{1,1,0}};
  constexpr int EA[12] = {0,0,0,0,1,1,1,1,2,2,2,2};
  for (int t = 0; t < NT; t++) {
    float B[3][3] = {};
    int ax[3] = {};
    for (int k = 0; k < 3; k++) {
      int e = tri[t][k];
      int a = EA[e];
      ax[k] = a;
      T.lofc[t][k] = ((a * 2 + EC[e][0]) * 7 + EC[e][1]) * 49 + EC[e][2];
      B[k][0] = (float)EC[e][0]; B[k][1] = (float)EC[e][1]; B[k][2] = (float)EC[e][2];
      B[k][a] += 0.5f;
    }
    for (int c = 0; c < 3; c++) {
      T.ub[t][c] = B[1][c] - B[0][c];
      T.wb[t][c] = B[2][c] - B[0][c];
    }
    T.a0[t] = ax[0]; T.a1[t] = ax[1]; T.a2[t] = ax[2];
    T.tto[t] = tt[t];
  }
  return T;
}

static constexpr TriTab3 TAB = make_tab();

// ---------------- kernels ----------------
template <int t>
__device__ __forceinline__ void do1(const float* __restrict__ loff, int lanebase,
                                    const float* __restrict__ myrow,
                                    float& s, float& mx, float& my, float& mz) {
  constexpr int L0 = TAB.lofc[t][0], L1 = TAB.lofc[t][1], L2 = TAB.lofc[t][2];
  constexpr int A0 = TAB.a0[t], A1 = TAB.a1[t], A2 = TAB.a2[t];
  float p  = myrow[TAB.tto[t]];
  float d0 = loff[lanebase + L0];
  float d1 = loff[lanebase + L1];
  float d2 = loff[lanebase + L2];
  float ux = TAB.ub[t][0] + (A1 == 0 ? d1 : 0.0f) - (A0 == 0 ? d0 : 0.0f);
  float uy = TAB.ub[t][1] + (A1 == 1 ? d1 : 0.0f) - (A0 == 1 ? d0 : 0.0f);
  float uz = TAB.ub[t][2] + (A1 == 2 ? d1 : 0.0f) - (A0 == 2 ? d0 : 0.0f);
  float wx = TAB.wb[t][0] + (A2 == 0 ? d2 : 0.0f) - (A0 == 0 ? d0 : 0.0f);
  float wy = TAB.wb[t][1] + (A2 == 1 ? d2 : 0.0f) - (A0 == 1 ? d0 : 0.0f);
  float wz = TAB.wb[t][2] + (A2 == 2 ? d2 : 0.0f) - (A0 == 2 ? d0 : 0.0f);
  float cxv = uy * wz - uz * wy;
  float cyv = uz * wx - ux * wz;
  float czv = ux * wy - uy * wx;
  float nn = cxv * cxv + cyv * cyv + czv * czv + 1e-8f;
  float rinv = rsqrtf(nn);
  s += p;
  float f = p * rinv;
  mx += f * cxv;
  my += f * cyv;
  mz += f * czv;
}

template <int T0>
__device__ __forceinline__ void do6(const float* __restrict__ loff, int lanebase,
                                    const float* __restrict__ myrow,
                                    float& s, float& mx, float& my, float& mz) {
  do1<T0 + 0>(loff, lanebase, myrow, s, mx, my, mz);
  do1<T0 + 1>(loff, lanebase, myrow, s, mx, my, mz);
  do1<T0 + 2>(loff, lanebase, myrow, s, mx, my, mz);
  do1<T0 + 3>(loff, lanebase, myrow, s, mx, my, mz);
  do1<T0 + 4>(loff, lanebase, myrow, s, mx, my, mz);
  do1<T0 + 5>(loff, lanebase, myrow, s, mx, my, mz);
}

// 432 blocks x 512 threads; each block pipelines 4 tiles of 64 cells with
// double-buffered topo LDS: prefetch t+1 into regs -> compute t -> ds_write
// prefetch -> one barrier -> distributed reduce. The vmcnt wait lands after
// compute instead of cold-stalling the block (R5-R7's structure).
__global__ __launch_bounds__(CB * NW, 4) void k_cell(const float* __restrict__ off,
                                                     const float* __restrict__ topo,
                                                     float4* __restrict__ ws4,
                                                     float* __restrict__ out) {
  __shared__ float tbuf[2][CB * PITCH];
  __shared__ float loff[OFFE];
  __shared__ float4 red[2][NW * 65];   // pitch 65 -> conflict-free reduce reads
  const int tid = threadIdx.x;
  const int lane = tid & 63;
  const int wv = tid >> 6;
  const int c00 = blockIdx.x * (CB * TILES);
  const int x0 = c00 / 2304;
  const int y0 = (c00 / 48) % 48;     // 2304 % 256 == 0 -> x const per block

  if (blockIdx.x == 0 && tid == 0) *out = 0.0f;  // zero accumulator for k_pair

  // ---- stage off region once: x0..x0+1, y0..y0+6, z 0..48 -> 2058 floats ----
  for (int e = tid; e < OFFE; e += CB * NW) {
    int zz = e % 49, r = e / 49;       // r = (a*2+dx)*7+ly
    int ly = r % 7, rr = r / 7;
    int dx = rr & 1, a = rr >> 1;
    loff[e] = off[a * 117649 + (x0 + dx) * 2401 + (y0 + ly) * 49 + zz];
  }
  // ---- stage tile 0 ----
  {
    const float4* trow = (const float4*)(topo + (size_t)c00 * 96);
#pragma unroll
    for (int it = 0; it < 3; ++it) {
      int ch = tid + 512 * it;
      float4 v = trow[ch];
      int r = ch / 24, c4 = (ch % 24) * 4;
      float* dst = &tbuf[0][r * PITCH + c4];
      dst[0] = v.x; dst[1] = v.y; dst[2] = v.z; dst[3] = v.w;
    }
  }
  __syncthreads();

  for (int t = 0; t < TILES; ++t) {
    const int bsel = t & 1;
    // ---- issue prefetch of tile t+1 into registers (no wait yet) ----
    float4 p0, p1, p2;
    const bool pf = (t + 1 < TILES);
    if (pf) {
      const float4* trow = (const float4*)(topo + (size_t)(c00 + (t + 1) * CB) * 96);
      p0 = trow[tid];
      p1 = trow[tid + 512];
      p2 = trow[tid + 1024];
    }

    // ---- compute tile t ----
    const int cell = c00 + t * CB + lane;
    const int z = cell % 48;
    const int ly = ((cell / 48) % 48) - y0;        // 0..5
    const int lanebase = ly * 49 + z;
    const float* myrow = &tbuf[bsel][lane * PITCH];

    float s = 0.f, mx = 0.f, my = 0.f, mz = 0.f;
    const int wvu = __builtin_amdgcn_readfirstlane(wv);  // SGPR-uniform
    if (wvu == 0)      do6<0>(loff, lanebase, myrow, s, mx, my, mz);
    else if (wvu == 1) do6<6>(loff, lanebase, myrow, s, mx, my, mz);
    else if (wvu == 2) do6<12>(loff, lanebase, myrow, s, mx, my, mz);
    else if (wvu == 3) do6<18>(loff, lanebase, myrow, s, mx, my, mz);
    else if (wvu == 4) do6<24>(loff, lanebase, myrow, s, mx, my, mz);
    else if (wvu == 5) do6<30>(loff, lanebase, myrow, s, mx, my, mz);
    else if (wvu == 6) do6<36>(loff, lanebase, myrow, s, mx, my, mz);
    else               do6<42>(loff, lanebase, myrow, s, mx, my, mz);

    red[bsel][wv * 65 + lane] = make_float4(s, mx, my, mz);

    // ---- write prefetch into the other topo buffer (vmcnt wait lands here) ----
    if (pf) {
#pragma unroll
      for (int it = 0; it < 3; ++it) {
        int ch = tid + 512 * it;
        float4 v = (it == 0) ? p0 : (it == 1) ? p1 : p2;
        int r = ch / 24, c4 = (ch % 24) * 4;
        float* dst = &tbuf[1 - bsel][r * PITCH + c4];
        dst[0] = v.x; dst[1] = v.y; dst[2] = v.z; dst[3] = v.w;
      }
    }
    __syncthreads();

    // ---- distributed reduce: wave wv sums cells [8wv, 8wv+8) of tile t ----
    {
      const int c = (wv << 3) + (lane >> 3);
      const int p = lane & 7;
      float4 v = red[bsel][p * 65 + c];
#pragma unroll
      for (int d = 1; d < 8; d <<= 1) {
        v.x += __shfl_xor(v.x, d, 64);
        v.y += __shfl_xor(v.y, d, 64);
        v.z += __shfl_xor(v.z, d, 64);
        v.w += __shfl_xor(v.w, d, 64);
      }
      if (p == 0) ws4[c00 + t * CB + c] = v;
    }
    // no trailing barrier: next iter uses the other red/topo buffers, and no
    // wave can be >1 barrier ahead.
  }
}

__global__ __launch_bounds__(256) void k_pair(const float4* __restrict__ ws4,
                                              float* __restrict__ out) {
  int cell = blockIdx.x * 256 + threadIdx.x;
  int z = cell % 48;
  int y = (cell / 48) % 48;
  int x = cell / 2304;
  float4 a = ws4[cell];
  float acc = a.x * a.x - (a.y * a.y + a.z * a.z + a.w * a.w);
  if (z < 47) {
    float4 b = ws4[cell + 1];
    acc += a.x * b.x - (a.y * b.y + a.z * b.z + a.w * b.w);
  }
  if (y < 47) {
    float4 b = ws4[cell + 48];
    acc += a.x * b.x - (a.y * b.y + a.z * b.z + a.w * b.w);
  }
  if (x < 47) {
    float4 b = ws4[cell + 2304];
    acc += a.x * b.x - (a.y * b.y + a.z * b.z + a.w * b.w);
  }
  acc *= 2.0f;
  for (int o = 32; o > 0; o >>= 1) acc += __shfl_down(acc, o, 64);
  __shared__ float lds[4];
  int lane = threadIdx.x & 63;
  int w = threadIdx.x >> 6;
  if (lane == 0) lds[w] = acc;
  __syncthreads();
  if (threadIdx.x == 0) atomicAdd(out, lds[0] + lds[1] + lds[2] + lds[3]);
}

extern "C" void kernel_launch(void* const* d_in, const int* in_sizes, int n_in,
                              void* d_out, int out_size, void* d_ws, size_t ws_size,
                              hipStream_t stream) {
  const float* off  = (const float*)d_in[0];   // [3,49,49,49] f32
  const float* topo = (const float*)d_in[1];   // [110592,96] f32
  float4* ws4 = (float4*)d_ws;                 // 110592 float4 = 1.77 MB
  float* out  = (float*)d_out;                 // scalar f32

  k_cell<<<dim3(NBLK), dim3(CB * NW), 0, stream>>>(off, topo, ws4, out);
  k_pair<<<dim3(NCELLS / 256), dim3(256), 0, stream>>>(ws4, out);
}